// Round 1
// baseline (304.533 us; speedup 1.0000x reference)
//
#include <hip/hip_runtime.h>

// PseudoImageScatter: img[f, y, x] = pillar_features[p, f], last pillar wins.
// Pass 1: winner[y*W+x] = atomicMax(pillar idx)  (last-wins == max idx)
// Pass 2: 256-cell tiles, feature-major LDS transpose, two f-halves of 32,
//         software-pipelined, 2 tiles per block.
//   Key changes vs previous version:
//   - Barriers are lgkmcnt(0)+s_barrier ONLY: __syncthreads() would drain
//     vmcnt(0), i.e. wait for the 8 in-flight nontemporal stores (~600-900 cy
//     HBM ack) four times per tile. LDS reuse only needs DS ops ordered.
//   - Half-1 gather rows prefetched into registers during half-0 consume;
//     next tile's winner+rows prefetched during half-1 consume.
//   - Branchless zero cells: load from row max(wp,0) (always valid, broadcast
//     L1 hit for losers) and cndmask with 0 -> no divergent 32-write zero path.

constexpr int H    = 1024;
constexpr int W    = 1024;
constexpr int HW   = H * W;
constexpr int NF   = 64;
constexpr int TILE = 256;           // cells per tile
constexpr int HALF = 32;            // features per LDS pass
constexpr int TPB  = 2;             // tiles per block

typedef float nt4 __attribute__((ext_vector_type(4)));  // native vec for nontemporal

__global__ void winner_kernel(const int* __restrict__ coords,
                              int* __restrict__ winner, int np) {
    int p = blockIdx.x * blockDim.x + threadIdx.x;
    if (p >= np) return;
    int y = coords[p * 3 + 1];
    int x = coords[p * 3 + 2];
    if ((unsigned)x < (unsigned)W && (unsigned)y < (unsigned)H) {
        atomicMax(winner + (y * W + x), p);   // device-scope, cross-XCD safe
    }
}

// LDS-only barrier: order my DS ops, then rendezvous. Deliberately does NOT
// drain vmcnt — nontemporal stores stay in flight across phases.
__device__ __forceinline__ void bar_lds() {
    asm volatile("s_waitcnt lgkmcnt(0)" ::: "memory");
    __builtin_amdgcn_s_barrier();
}

__global__ void __launch_bounds__(256) fill_kernel(const float* __restrict__ feat,
                                                   const int* __restrict__ winner,
                                                   float* __restrict__ out) {
    __shared__ float lds[HALF * TILE];        // 32 KiB -> 5 blocks/CU
    const int t  = threadIdx.x;               // cell within tile (phase A)
    const int wv = t >> 6;                    // wave id 0..3
    const int l  = t & 63;                    // lane

    const int base = blockIdx.x * (TILE * TPB);

    const float4 z4 = make_float4(0.f, 0.f, 0.f, 0.f);
    float4 r[8];                              // staging regs (one half-row)

    // --- prologue: tile 0, half 0 gather ---
    int wp = winner[base + t];                // coalesced
    const float4* row = (const float4*)(feat + (size_t)max(wp, 0) * NF);
    bool valid = wp >= 0;
#pragma unroll
    for (int j = 0; j < 8; ++j) { float4 v = row[j]; r[j] = valid ? v : z4; }

    for (int tile = 0; tile < TPB; ++tile) {
        const int tb = base + tile * TILE;

        // ---- stage half 0 (f-major: lds[f*256+c], bank=c%32, 2-way = free)
#pragma unroll
        for (int j = 0; j < 8; ++j) {
            lds[(4 * j + 0) * TILE + t] = r[j].x;
            lds[(4 * j + 1) * TILE + t] = r[j].y;
            lds[(4 * j + 2) * TILE + t] = r[j].z;
            lds[(4 * j + 3) * TILE + t] = r[j].w;
        }
        bar_lds();

        // ---- prefetch half 1 rows into regs (hidden under consume below)
#pragma unroll
        for (int j = 0; j < 8; ++j) { float4 v = row[8 + j]; r[j] = valid ? v : z4; }

        // ---- consume half 0: wave wv writes planes f = p*4+wv,
        // 64 lanes x 16 B = 1 KiB contiguous nontemporal per instruction.
#pragma unroll
        for (int p = 0; p < 8; ++p) {
            const int f = p * 4 + wv;
            nt4 v = *(const nt4*)&lds[f * TILE + l * 4];
            __builtin_nontemporal_store(
                v, (nt4*)(out + (size_t)f * HW + tb + l * 4));
        }
        bar_lds();                            // all ds_reads done -> LDS reusable

        // ---- stage half 1
#pragma unroll
        for (int j = 0; j < 8; ++j) {
            lds[(4 * j + 0) * TILE + t] = r[j].x;
            lds[(4 * j + 1) * TILE + t] = r[j].y;
            lds[(4 * j + 2) * TILE + t] = r[j].z;
            lds[(4 * j + 3) * TILE + t] = r[j].w;
        }
        bar_lds();

        // ---- prefetch next tile's winner + half-0 rows (hidden under consume)
        if (tile + 1 < TPB) {
            wp    = winner[base + (tile + 1) * TILE + t];
            row   = (const float4*)(feat + (size_t)max(wp, 0) * NF);
            valid = wp >= 0;
#pragma unroll
            for (int j = 0; j < 8; ++j) { float4 v = row[j]; r[j] = valid ? v : z4; }
        }

        // ---- consume half 1
#pragma unroll
        for (int p = 0; p < 8; ++p) {
            const int floc = p * 4 + wv;
            nt4 v = *(const nt4*)&lds[floc * TILE + l * 4];
            __builtin_nontemporal_store(
                v, (nt4*)(out + (size_t)(HALF + floc) * HW + tb + l * 4));
        }
        if (tile + 1 < TPB) bar_lds();        // before next tile reuses LDS
    }
}

extern "C" void kernel_launch(void* const* d_in, const int* in_sizes, int n_in,
                              void* d_out, int out_size, void* d_ws, size_t ws_size,
                              hipStream_t stream) {
    const float* feat   = (const float*)d_in[0];
    const int*   coords = (const int*)d_in[1];
    float*       out    = (float*)d_out;
    int np = in_sizes[1] / 3;

    int* winner = (int*)d_ws;   // HW ints = 4 MiB scratch

    (void)hipMemsetAsync(winner, 0xFF, (size_t)HW * sizeof(int), stream);  // winner := -1
    winner_kernel<<<(np + 255) / 256, 256, 0, stream>>>(coords, winner, np);
    fill_kernel<<<HW / (TILE * TPB), 256, 0, stream>>>(feat, winner, out);
}

// Round 2
// 295.684 us; speedup vs baseline: 1.0299x; 1.0299x over previous
//
#include <hip/hip_runtime.h>

// PseudoImageScatter: img[f, y, x] = pillar_features[p, f], last pillar wins.
// Pass 1: winner[y*W+x] = atomicMax(pillar idx)  (last-wins == max idx)
// Pass 2: burst-oriented transpose. Block = 2048 cells, 16 passes of 4
//         features. Per pass each of the 4 waves writes ONE plane as an
//         8 KB sequential burst (8 back-to-back 1 KiB nt4 stores).
//   Rationale: previous version fanned each block's 64 KB across 64 planes
//   4 MB apart in 1 KB chunks -> thousands of interleaved DRAM write streams
//   -> row-buffer thrash (~2.3 TB/s effective). This version emits 4 streams
//   per block with 8 KB sequential bursts.
//   - Barriers are lgkmcnt(0)+s_barrier only (never drain vmcnt: stores and
//     prefetch loads stay in flight).
//   - Next pass's gathers (one float4 = 16 B per cell) prefetched into regs
//     during the store burst.
//   - Branchless zero cells: gather row max(wp,0) (broadcast L1 hit for
//     invalid) and select 0.

constexpr int H    = 1024;
constexpr int W    = 1024;
constexpr int HW   = H * W;
constexpr int NF   = 64;
constexpr int TILE = 2048;          // cells per block
constexpr int CPT  = TILE / 256;    // cells per thread = 8
constexpr int FP   = 4;             // features per pass (== waves per block)
constexpr int NP   = NF / FP;       // 16 passes

typedef float nt4 __attribute__((ext_vector_type(4)));

__global__ void winner_kernel(const int* __restrict__ coords,
                              int* __restrict__ winner, int np) {
    int p = blockIdx.x * blockDim.x + threadIdx.x;
    if (p >= np) return;
    int y = coords[p * 3 + 1];
    int x = coords[p * 3 + 2];
    if ((unsigned)x < (unsigned)W && (unsigned)y < (unsigned)H) {
        atomicMax(winner + (y * W + x), p);   // device-scope, cross-XCD safe
    }
}

// LDS-only barrier: order my DS ops, then rendezvous. Does NOT drain vmcnt —
// nontemporal stores / prefetch loads stay in flight across phases.
__device__ __forceinline__ void bar_lds() {
    asm volatile("s_waitcnt lgkmcnt(0)" ::: "memory");
    __builtin_amdgcn_s_barrier();
}

__global__ void __launch_bounds__(256) fill_kernel(const float* __restrict__ feat,
                                                   const int* __restrict__ winner,
                                                   float* __restrict__ out) {
    __shared__ float lds[FP * TILE];          // 4 x 2048 x 4 B = 32 KiB
    const int t  = threadIdx.x;
    const int wv = t >> 6;                    // wave id 0..3  -> feature-in-pass
    const int l  = t & 63;                    // lane
    const int tb = blockIdx.x * TILE;

    const float4 z4 = make_float4(0.f, 0.f, 0.f, 0.f);

    // Per-thread cells: cc = k*256 + t (lane-contiguous per k chunk).
    const float4* row[CPT];
    bool          ok[CPT];
#pragma unroll
    for (int k = 0; k < CPT; ++k) {
        int wp = winner[tb + k * 256 + t];    // coalesced
        ok[k]  = wp >= 0;
        row[k] = (const float4*)(feat + (size_t)max(wp, 0) * NF);
    }

    float4 g[2][CPT];                         // double-buffered gather regs
#pragma unroll
    for (int k = 0; k < CPT; ++k) {           // prefetch pass 0 (features 0..3)
        float4 v = row[k][0];
        g[0][k] = ok[k] ? v : z4;
    }

#pragma unroll
    for (int p = 0; p < NP; ++p) {            // fully unrolled -> static g idx
        const int cur = p & 1;

        // ---- stage: lds[q*TILE + cc] = feature (4p+q) of cell cc.
        // Lane-contiguous b32 writes: bank = cc%32, 2-way alias = free.
#pragma unroll
        for (int k = 0; k < CPT; ++k) {
            const int cc = k * 256 + t;
            lds[0 * TILE + cc] = g[cur][k].x;
            lds[1 * TILE + cc] = g[cur][k].y;
            lds[2 * TILE + cc] = g[cur][k].z;
            lds[3 * TILE + cc] = g[cur][k].w;
        }
        bar_lds();

        // ---- prefetch next pass's gathers (hidden under the store burst)
        if (p + 1 < NP) {
#pragma unroll
            for (int k = 0; k < CPT; ++k) {
                float4 v = row[k][p + 1];
                g[cur ^ 1][k] = ok[k] ? v : z4;
            }
        }

        // ---- store burst: wave wv owns plane f = 4p + wv, writes
        // cells tb..tb+2047 as 8 consecutive 1 KiB nt4 stores = 8 KiB seq.
        float* dst = out + (size_t)(p * FP + wv) * HW + tb;
#pragma unroll
        for (int j = 0; j < TILE / 256; ++j) {
            nt4 v = *(const nt4*)&lds[wv * TILE + j * 256 + l * 4];
            __builtin_nontemporal_store(v, (nt4*)(dst + j * 256 + l * 4));
        }
        bar_lds();                            // ds_reads done -> LDS reusable
    }
}

extern "C" void kernel_launch(void* const* d_in, const int* in_sizes, int n_in,
                              void* d_out, int out_size, void* d_ws, size_t ws_size,
                              hipStream_t stream) {
    const float* feat   = (const float*)d_in[0];
    const int*   coords = (const int*)d_in[1];
    float*       out    = (float*)d_out;
    int np = in_sizes[1] / 3;

    int* winner = (int*)d_ws;   // HW ints = 4 MiB scratch

    (void)hipMemsetAsync(winner, 0xFF, (size_t)HW * sizeof(int), stream);  // winner := -1
    winner_kernel<<<(np + 255) / 256, 256, 0, stream>>>(coords, winner, np);
    fill_kernel<<<HW / TILE, 256, 0, stream>>>(feat, winner, out);
}